// Round 5
// baseline (582.955 us; speedup 1.0000x reference)
//
#include <hip/hip_runtime.h>

#define QLEN 1024
#define MLEN 1024
#define KLEN 2048
#define BATCH 4
#define NHEAD 16
#define DHEAD 64
#define DMODEL 1024

typedef _Float16 half8 __attribute__((ext_vector_type(8)));
typedef _Float16 half4 __attribute__((ext_vector_type(4)));
typedef float f32x4 __attribute__((ext_vector_type(4)));

#define NEG_INF (-__builtin_inff())
#define QSCALE 0.18033688011112042f /* 0.125 * log2(e) */

typedef __attribute__((address_space(3))) unsigned int lds_u32;
typedef __attribute__((address_space(1))) unsigned int glb_u32;

__device__ __forceinline__ void gll16(void* lds, const void* g) {
  __builtin_amdgcn_global_load_lds((const glb_u32*)g, (lds_u32*)lds, 16, 0, 0);
}

// ---------------------------------------------------------------------------
// Merged prep:
//   z=0 WqkvT, z=1 WrT, z=2 WoT (fp32->f16 64x64 transposes)
//   z=3 conv rel_pos->RelP (grid-stride), z=4 pack [mems;content]->Acat
// ---------------------------------------------------------------------------
__global__ __launch_bounds__(256) void k_prep(const float* __restrict__ Wqkv,
                                              const float* __restrict__ Wr,
                                              const float* __restrict__ Wo,
                                              const float* __restrict__ rel_pos,
                                              const float* __restrict__ mems,
                                              const float* __restrict__ content,
                                              _Float16* __restrict__ WqkvT,
                                              _Float16* __restrict__ WrT,
                                              _Float16* __restrict__ WoT,
                                              _Float16* __restrict__ RelP,
                                              _Float16* __restrict__ Acat)
{
  __shared__ float T[64][65];
  const int z = blockIdx.z;
  const int tid = threadIdx.x;
  if (z == 3) {
    int nb = gridDim.x * gridDim.y;
    int bid = blockIdx.y * gridDim.x + blockIdx.x;
    for (int e = (bid * 256 + tid) * 4; e < KLEN * DMODEL; e += nb * 256 * 4) {
      float4 v = *(const float4*)(rel_pos + e);
      half4 o = { (_Float16)v.x, (_Float16)v.y, (_Float16)v.z, (_Float16)v.w };
      *(half4*)(RelP + e) = o;
    }
    return;
  }
  if (z == 4) {
    int nb = gridDim.x * gridDim.y;
    int bid = blockIdx.y * gridDim.x + blockIdx.x;
    for (int e = (bid * 256 + tid) * 4; e < 8192 * DMODEL; e += nb * 256 * 4) {
      int m = e >> 10, kk = e & 1023;
      int crow = m >> 2, bb = m & 3;
      const float* src;
      if (crow < MLEN) src = mems + (size_t)(crow * BATCH + bb) * DMODEL + kk;
      else             src = content + (size_t)((crow - MLEN) * BATCH + bb) * DMODEL + kk;
      float4 v = *(const float4*)src;
      half4 o = { (_Float16)v.x, (_Float16)v.y, (_Float16)v.z, (_Float16)v.w };
      *(half4*)(Acat + (size_t)m * DMODEL + kk) = o;
    }
    return;
  }
  const float* in; _Float16* out; int C;
  if (z == 0)      { in = Wqkv; out = WqkvT; C = 3072; }
  else if (z == 1) { if (blockIdx.x >= 16) return; in = Wr; out = WrT; C = 1024; }
  else             { if (blockIdx.x >= 16) return; in = Wo; out = WoT; C = 1024; }
  const int R = 1024;
  int c0 = blockIdx.x * 64, r0 = blockIdx.y * 64;
#pragma unroll
  for (int u = 0; u < 16; ++u) {
    int lin = u * 256 + tid;
    int rr = lin >> 6, cc = lin & 63;
    T[rr][cc] = in[(size_t)(r0 + rr) * C + c0 + cc];
  }
  __syncthreads();
#pragma unroll
  for (int u = 0; u < 16; ++u) {
    int lin = u * 256 + tid;
    int cc = lin >> 6, rr = lin & 63;
    out[(size_t)(c0 + cc) * R + r0 + rr] = (_Float16)T[rr][cc];
  }
}

// per (b,h): V [2048][64] -> V^T [64][2048]
__global__ __launch_bounds__(256) void k_trans_v(const _Float16* __restrict__ Vb,
                                                 _Float16* __restrict__ VbT)
{
  __shared__ _Float16 T[64][72];
  int r0 = blockIdx.x * 64;
  int bh = blockIdx.y;
  const _Float16* in = Vb + (size_t)bh * KLEN * DHEAD;
  _Float16* out = VbT + (size_t)bh * DHEAD * KLEN;
  int tid = threadIdx.x;
#pragma unroll
  for (int u = 0; u < 16; ++u) {
    int lin = u * 256 + tid;
    int rr = lin >> 6, cc = lin & 63;
    T[rr][cc] = in[(size_t)(r0 + rr) * DHEAD + cc];
  }
  __syncthreads();
#pragma unroll
  for (int u = 0; u < 16; ++u) {
    int lin = u * 256 + tid;
    int cc = lin >> 6, rr = lin & 63;
    out[(size_t)cc * KLEN + r0 + rr] = T[rr][cc];
  }
}

// ---------------------------------------------------------------------------
// 128x128 MFMA GEMM core, async global->LDS staging; shared mem passed in so
// multiple instantiations in one kernel share the same LDS.
// ---------------------------------------------------------------------------
template<typename Epi>
__device__ __forceinline__ void gemm_tile_128(const _Float16* __restrict__ A,
                                              const _Float16* __restrict__ B,
                                              int K, int m0, int n0,
                                              _Float16* As, _Float16* Bs, Epi epi)
{
  const int tid = threadIdx.x;
  const int lane = tid & 63;
  const int wave = tid >> 6;
  const int q = lane >> 4, l16 = lane & 15;
  const int wm = wave >> 1, wn = wave & 1;
  f32x4 acc[4][4] = {};

  for (int k0 = 0; k0 < K; k0 += 32) {
    __syncthreads();
#pragma unroll
    for (int i = 0; i < 2; ++i) {
      int c = i * 256 + tid;
      int row = c >> 2, pos = c & 3;
      int col8 = pos ^ ((row >> 1) & 3);
      gll16(&As[c * 8], A + (size_t)(m0 + row) * K + k0 + col8 * 8);
      gll16(&Bs[c * 8], B + (size_t)(n0 + row) * K + k0 + col8 * 8);
    }
    __syncthreads();
    half8 a[4], b[4];
#pragma unroll
    for (int rt = 0; rt < 4; ++rt) {
      int row = wm * 64 + rt * 16 + l16;
      a[rt] = *(const half8*)&As[(row * 4 + (q ^ ((row >> 1) & 3))) * 8];
    }
#pragma unroll
    for (int ct = 0; ct < 4; ++ct) {
      int row = wn * 64 + ct * 16 + l16;
      b[ct] = *(const half8*)&Bs[(row * 4 + (q ^ ((row >> 1) & 3))) * 8];
    }
#pragma unroll
    for (int rt = 0; rt < 4; ++rt)
#pragma unroll
      for (int ct = 0; ct < 4; ++ct)
        acc[rt][ct] = __builtin_amdgcn_mfma_f32_16x16x32_f16(a[rt], b[ct], acc[rt][ct], 0, 0, 0);
  }
#pragma unroll
  for (int rt = 0; rt < 4; ++rt)
#pragma unroll
    for (int ct = 0; ct < 4; ++ct)
#pragma unroll
      for (int reg = 0; reg < 4; ++reg) {
        int m = m0 + wm * 64 + rt * 16 + q * 4 + reg;
        int nn = n0 + wn * 64 + ct * 16 + l16;
        epi(m, nn, acc[rt][ct][reg]);
      }
}

// GEMM1+2 merged: by<64 -> cat@W_qkv scatter epilogue; by>=64 -> RelP@WrT -> Rk2
__global__ __launch_bounds__(256, 2) void k_gemm_qkv_rk(
    const _Float16* __restrict__ A, const _Float16* __restrict__ B,
    const _Float16* __restrict__ RelP, const _Float16* __restrict__ WrT,
    _Float16* __restrict__ Qw, _Float16* __restrict__ Qr,
    _Float16* __restrict__ Kb, _Float16* __restrict__ Vb,
    _Float16* __restrict__ Rk2,
    const float* __restrict__ rwb, const float* __restrict__ rrb)
{
  __shared__ __align__(16) _Float16 As[128 * 32];
  __shared__ __align__(16) _Float16 Bs[128 * 32];
  const int bx = blockIdx.x, by = blockIdx.y;
  if (by >= 64) {                                  // rk tiles
    if (bx >= 8) return;
    gemm_tile_128(RelP, WrT, DMODEL, (by - 64) * 128, bx * 128, As, Bs,
      [=](int m, int nn, float v) {
        int hh = nn >> 6, dd = nn & 63;
        Rk2[((size_t)hh * KLEN + m) * DHEAD + dd] = (_Float16)v;
      });
    return;
  }
  if (bx < 8 && by < 32) return;                   // q-section for mem rows unused
  const int sec = bx >> 3;                          // uniform per block
  gemm_tile_128(A, B, DMODEL, by * 128, bx * 128, As, Bs,
    [=](int m, int nn, float v) {
      int c = nn & 1023;
      int hh = c >> 6, dd = c & 63;
      int crow = m >> 2, bb = m & 3;
      int bhh = bb * NHEAD + hh;
      if (sec == 0) {
        int i = crow - MLEN;
        size_t o = ((size_t)bhh * QLEN + i) * DHEAD + dd;
        Qw[o] = (_Float16)((v + rwb[c]) * QSCALE);
        Qr[o] = (_Float16)((v + rrb[c]) * QSCALE);
      } else if (sec == 1) {
        Kb[((size_t)bhh * KLEN + crow) * DHEAD + dd] = (_Float16)v;
      } else {
        Vb[((size_t)bhh * KLEN + crow) * DHEAD + dd] = (_Float16)v;
      }
    });
}

// GEMM3: attn_vec @ W_o + content -> Y (fp32)
__global__ __launch_bounds__(256, 2) void k_gemm_out(
    const _Float16* __restrict__ A, const _Float16* __restrict__ B,
    const float* __restrict__ content, float* __restrict__ Y)
{
  __shared__ __align__(16) _Float16 As[128 * 32];
  __shared__ __align__(16) _Float16 Bs[128 * 32];
  gemm_tile_128(A, B, DMODEL, blockIdx.y * 128, blockIdx.x * 128, As, Bs,
    [=](int m, int nn, float v) {
      Y[(size_t)m * DMODEL + nn] = v + content[(size_t)m * DMODEL + nn];
    });
}

// ---------------------------------------------------------------------------
// Flash attention w/ XL relative shift. 64-row Q-blocks, 1 row-group/wave.
//  - ALL 10 r_k loads issued up-front per tile: their ~200cy L2 latency is
//    covered by the staging issue + AC's ds_read+MFMA chain (~300cy)
//  - max-free online softmax (pre-scaled scores, exp2; |s| bounded)
//  - rel-shift via intra-16-group shuffles (no LDS round-trip)
//  - double-buffered async K/V staging, one barrier per j-tile
// ---------------------------------------------------------------------------
__global__ __launch_bounds__(256, 4) void k_attn(
    const _Float16* __restrict__ Qw, const _Float16* __restrict__ Qr,
    const _Float16* __restrict__ Kb, const _Float16* __restrict__ VbT,
    const _Float16* __restrict__ Rk2, _Float16* __restrict__ AV)
{
  __shared__ __align__(16) _Float16 Kl[2][64 * 64];     // [j][d], chunk-swizzled
  __shared__ __align__(16) _Float16 Vtl[2][64 * 64];    // [d][j], chunk-swizzled
  __shared__ __align__(16) _Float16 Pl[4][16 * 64];     // per-wave P

  const int tid = threadIdx.x;
  const int lane = tid & 63, wave = tid >> 6;
  const int q = lane >> 4, l16 = lane & 15;
  const int i0 = (15 - blockIdx.x) * 64;                // longest blocks first
  const int bh = blockIdx.y;
  const int h = bh & 15, bb = bh >> 4;

  const _Float16* Qwb = Qw + (size_t)bh * QLEN * DHEAD;
  const _Float16* Qrb = Qr + (size_t)bh * QLEN * DHEAD;
  const _Float16* Kbb = Kb + (size_t)bh * KLEN * DHEAD;
  const _Float16* Vtb = VbT + (size_t)bh * DHEAD * KLEN;
  const _Float16* Rkb = Rk2 + (size_t)h * KLEN * DHEAD;

  const int iw = i0 + wave * 16;
  const int lim = iw + 15 + MLEN;

  half8 aqw[2], aqr[2];
#pragma unroll
  for (int s = 0; s < 2; ++s) {
    size_t o = (size_t)(iw + l16) * DHEAD + s * 32 + q * 8;
    aqw[s] = *(const half8*)(Qwb + o);
    aqr[s] = *(const half8*)(Qrb + o);
  }

  f32x4 oa[4] = {};
  float l_lane[4] = {};
  _Float16* Plw = &Pl[wave][0];

  auto stage = [&](int j0s, int bufi) {
#pragma unroll
    for (int i = 0; i < 2; ++i) {
      int c = i * 256 + tid;
      int row = c >> 3;
      int col8 = (c & 7) ^ (row & 7);
      gll16(&Kl[bufi][c * 8],  Kbb + (size_t)(j0s + row) * DHEAD + col8 * 8);
      gll16(&Vtl[bufi][c * 8], Vtb + (size_t)row * KLEN + j0s + col8 * 8);
    }
  };

  const int n_jt = (i0 >> 6) + 17;
  stage(0, 0);
  for (int jt = 0; jt < n_jt; ++jt) {
    const int j0 = jt * 64;
    const int bufi = jt & 1;
    __syncthreads();                              // publish buf[bufi], free other

    const bool act = (j0 <= lim);
    // all 10 r_k loads for THIS tile, issued before staging + AC
    half8 rk[5][2];
    if (act) {
      const int rs = j0 - iw + 1008;
#pragma unroll
      for (int rt = 0; rt < 5; ++rt) {
        int r = rs + rt * 16 + l16;
        int rc = r < 0 ? 0 : (r > KLEN - 1 ? KLEN - 1 : r);  // clamped rows
        const _Float16* base = Rkb + (size_t)rc * DHEAD + q * 8;  // feed only
        rk[rt][0] = *(const half8*)(base);                        // masked cols
        rk[rt][1] = *(const half8*)(base + 32);
      }
    }
    if (jt + 1 < n_jt) stage((jt + 1) * 64, bufi ^ 1);
    if (!act) continue;                           // fully masked for this wave

    const _Float16* Klb = Kl[bufi];
    const _Float16* Vtlb = Vtl[bufi];

    // AC: Qw @ K^T from LDS (covers rk load latency)
    f32x4 ac[4] = {};
#pragma unroll
    for (int ct = 0; ct < 4; ++ct) {
      int row = ct * 16 + l16;
#pragma unroll
      for (int s = 0; s < 2; ++s) {
        int pos = (s * 4 + q) ^ (row & 7);
        half8 bk = *(const half8*)&Klb[(row * 8 + pos) * 8];
        ac[ct] = __builtin_amdgcn_mfma_f32_16x16x32_f16(aqw[s], bk, ac[ct], 0, 0, 0);
      }
    }

    // BD: Qr @ r_k_window^T (data already resident)
    f32x4 bd[5] = {};
#pragma unroll
    for (int rt = 0; rt < 5; ++rt) {
      bd[rt] = __builtin_amdgcn_mfma_f32_16x16x32_f16(aqr[0], rk[rt][0], bd[rt], 0, 0, 0);
      bd[rt] = __builtin_amdgcn_mfma_f32_16x16x32_f16(aqr[1], rk[rt][1], bd[rt], 0, 0, 0);
    }

    // score: shuffle rel-shift + mask + exp2 -> Pl (per-wave, no barrier)
    const bool boundary = (j0 + 63 > iw + MLEN);
#pragma unroll
    for (int reg = 0; reg < 4; ++reg) {
      const int m = q * 4 + reg;                  // uniform within 16-group
      const int src = (l16 + 15 - m) & 15;
      float sh[5];
#pragma unroll
      for (int rt = 0; rt < 5; ++rt) sh[rt] = __shfl(bd[rt][reg], src, 16);
      const bool sel = (l16 > m);
      float acc = 0.f;
#pragma unroll
      for (int ct = 0; ct < 4; ++ct) {
        float bdv = sel ? sh[ct + 1] : sh[ct];
        float sv = ac[ct][reg] + bdv;
        if (boundary && (j0 + ct * 16 + l16 > iw + m + MLEN)) sv = NEG_INF;
        float e = __builtin_amdgcn_exp2f(sv);
        acc += e;
        int c = ct * 16 + l16;
        Plw[m * 64 + (((c >> 3) ^ (m & 7)) * 8) + (c & 7)] = (_Float16)e;
      }
      l_lane[reg] += acc;
    }

    // PV: O += P @ V
    half8 ap[2];
#pragma unroll
    for (int s = 0; s < 2; ++s)
      ap[s] = *(const half8*)&Plw[l16 * 64 + (((s * 4 + q) ^ (l16 & 7)) * 8)];
#pragma unroll
    for (int t = 0; t < 4; ++t) {
      int row = t * 16 + l16;
#pragma unroll
      for (int s = 0; s < 2; ++s) {
        int pos = (s * 4 + q) ^ (row & 7);
        half8 bv = *(const half8*)&Vtlb[(row * 8 + pos) * 8];
        oa[t] = __builtin_amdgcn_mfma_f32_16x16x32_f16(ap[s], bv, oa[t], 0, 0, 0);
      }
    }
  }

  float linv[4];
#pragma unroll
  for (int reg = 0; reg < 4; ++reg) {
    float v = l_lane[reg];
    v += __shfl_xor(v, 1, 16);
    v += __shfl_xor(v, 2, 16);
    v += __shfl_xor(v, 4, 16);
    v += __shfl_xor(v, 8, 16);
    linv[reg] = 1.0f / v;
  }
#pragma unroll
  for (int t = 0; t < 4; ++t)
#pragma unroll
    for (int reg = 0; reg < 4; ++reg) {
      int ii = iw + q * 4 + reg;
      AV[(size_t)(ii * BATCH + bb) * DMODEL + h * DHEAD + t * 16 + l16] =
          (_Float16)(oa[t][reg] * linv[reg]);
    }
}

// ---------------------------------------------------------------------------
__global__ __launch_bounds__(256) void k_ln(const float* __restrict__ Y,
                                            const float* __restrict__ gamma,
                                            const float* __restrict__ beta,
                                            float* __restrict__ out)
{
  int row = blockIdx.x, tid = threadIdx.x;
  const float4 v = ((const float4*)(Y + (size_t)row * DMODEL))[tid];
  float s = v.x + v.y + v.z + v.w;
  float ss = v.x * v.x + v.y * v.y + v.z * v.z + v.w * v.w;
#pragma unroll
  for (int off = 32; off >= 1; off >>= 1) {
    s += __shfl_xor(s, off, 64);
    ss += __shfl_xor(ss, off, 64);
  }
  __shared__ float red[8];
  int wave = tid >> 6, lane = tid & 63;
  if (lane == 0) { red[wave] = s; red[4 + wave] = ss; }
  __syncthreads();
  s = red[0] + red[1] + red[2] + red[3];
  ss = red[4] + red[5] + red[6] + red[7];
  float mu = s * (1.0f / DMODEL);
  float var = ss * (1.0f / DMODEL) - mu * mu;
  float rstd = rsqrtf(var + 1e-5f);
  const float4 g = ((const float4*)gamma)[tid];
  const float4 bt = ((const float4*)beta)[tid];
  float4 o;
  o.x = (v.x - mu) * rstd * g.x + bt.x;
  o.y = (v.y - mu) * rstd * g.y + bt.y;
  o.z = (v.z - mu) * rstd * g.z + bt.z;
  o.w = (v.w - mu) * rstd * g.w + bt.w;
  ((float4*)(out + (size_t)row * DMODEL))[tid] = o;
}

// ---------------------------------------------------------------------------
extern "C" void kernel_launch(void* const* d_in, const int* in_sizes, int n_in,
                              void* d_out, int out_size, void* d_ws, size_t ws_size,
                              hipStream_t stream)
{
  (void)in_sizes; (void)n_in; (void)out_size; (void)ws_size;
  const float* content = (const float*)d_in[0];
  const float* rel_pos = (const float*)d_in[1];
  const float* mems    = (const float*)d_in[2];
  const float* rwb     = (const float*)d_in[3];
  const float* rrb     = (const float*)d_in[4];
  const float* Wqkv    = (const float*)d_in[5];
  const float* Wr      = (const float*)d_in[6];
  const float* Wo      = (const float*)d_in[7];
  const float* gamma   = (const float*)d_in[8];
  const float* beta    = (const float*)d_in[9];

  char* ws = (char*)d_ws;
  size_t off = 0;
  auto take = [&](size_t bytes) { char* p = ws + off; off += (bytes + 255) & ~(size_t)255; return p; };

  _Float16* Acat  = (_Float16*)take(8192ull * 1024 * 2);      // reused as VbT
  _Float16* WqkvT = (_Float16*)take(3072ull * 1024 * 2);
  _Float16* RelP  = (_Float16*)take(2048ull * 1024 * 2);
  _Float16* WrT   = (_Float16*)take(1024ull * 1024 * 2);
  _Float16* WoT   = (_Float16*)take(1024ull * 1024 * 2);
  _Float16* Qw    = (_Float16*)take(64ull * 1024 * 64 * 2);
  _Float16* Qr    = (_Float16*)take(64ull * 1024 * 64 * 2);
  _Float16* Kb    = (_Float16*)take(64ull * 2048 * 64 * 2);   // reused as Y (fp32)
  _Float16* Vb    = (_Float16*)take(64ull * 2048 * 64 * 2);
  _Float16* AV    = (_Float16*)take(4096ull * 1024 * 2);
  _Float16* Rk2   = (_Float16*)take(16ull * 2048 * 64 * 2);   // own buffer now
  _Float16* VbT   = Acat;   // Acat dead after k_gemm_qkv_rk
  float*    Y     = (float*)Kb;  // Kb dead after k_attn
  float*    out   = (float*)d_out;

  k_prep<<<dim3(48, 16, 5), dim3(256), 0, stream>>>(Wqkv, Wr, Wo, rel_pos, mems, content,
                                                    WqkvT, WrT, WoT, RelP, Acat);
  k_gemm_qkv_rk<<<dim3(24, 80), dim3(256), 0, stream>>>(Acat, WqkvT, RelP, WrT,
                                                        Qw, Qr, Kb, Vb, Rk2, rwb, rrb);
  k_trans_v<<<dim3(32, 64), dim3(256), 0, stream>>>(Vb, VbT);
  k_attn<<<dim3(16, 64), dim3(256), 0, stream>>>(Qw, Qr, Kb, VbT, Rk2, AV);
  k_gemm_out<<<dim3(8, 32), dim3(256), 0, stream>>>(AV, WoT, content, Y);
  k_ln<<<dim3(4096), dim3(256), 0, stream>>>(Y, gamma, beta, out);
}

// Round 6
// 450.816 us; speedup vs baseline: 1.2931x; 1.2931x over previous
//
#include <hip/hip_runtime.h>

#define QLEN 1024
#define MLEN 1024
#define KLEN 2048
#define BATCH 4
#define NHEAD 16
#define DHEAD 64
#define DMODEL 1024

typedef _Float16 half8 __attribute__((ext_vector_type(8)));
typedef _Float16 half4 __attribute__((ext_vector_type(4)));
typedef float f32x4 __attribute__((ext_vector_type(4)));

#define NEG_INF (-__builtin_inff())
#define QSCALE 0.18033688011112042f /* 0.125 * log2(e) */

typedef __attribute__((address_space(3))) unsigned int lds_u32;
typedef __attribute__((address_space(1))) unsigned int glb_u32;

__device__ __forceinline__ void gll16(void* lds, const void* g) {
  __builtin_amdgcn_global_load_lds((const glb_u32*)g, (lds_u32*)lds, 16, 0, 0);
}

// ---------------------------------------------------------------------------
// Merged prep:
//   z=0 WqkvT, z=1 WrT, z=2 WoT (fp32->f16 64x64 transposes)
//   z=3 conv rel_pos->RelP (grid-stride), z=4 pack [mems;content]->Acat
// ---------------------------------------------------------------------------
__global__ __launch_bounds__(256) void k_prep(const float* __restrict__ Wqkv,
                                              const float* __restrict__ Wr,
                                              const float* __restrict__ Wo,
                                              const float* __restrict__ rel_pos,
                                              const float* __restrict__ mems,
                                              const float* __restrict__ content,
                                              _Float16* __restrict__ WqkvT,
                                              _Float16* __restrict__ WrT,
                                              _Float16* __restrict__ WoT,
                                              _Float16* __restrict__ RelP,
                                              _Float16* __restrict__ Acat)
{
  __shared__ float T[64][65];
  const int z = blockIdx.z;
  const int tid = threadIdx.x;
  if (z == 3) {
    int nb = gridDim.x * gridDim.y;
    int bid = blockIdx.y * gridDim.x + blockIdx.x;
    for (int e = (bid * 256 + tid) * 4; e < KLEN * DMODEL; e += nb * 256 * 4) {
      float4 v = *(const float4*)(rel_pos + e);
      half4 o = { (_Float16)v.x, (_Float16)v.y, (_Float16)v.z, (_Float16)v.w };
      *(half4*)(RelP + e) = o;
    }
    return;
  }
  if (z == 4) {
    int nb = gridDim.x * gridDim.y;
    int bid = blockIdx.y * gridDim.x + blockIdx.x;
    for (int e = (bid * 256 + tid) * 4; e < 8192 * DMODEL; e += nb * 256 * 4) {
      int m = e >> 10, kk = e & 1023;
      int crow = m >> 2, bb = m & 3;
      const float* src;
      if (crow < MLEN) src = mems + (size_t)(crow * BATCH + bb) * DMODEL + kk;
      else             src = content + (size_t)((crow - MLEN) * BATCH + bb) * DMODEL + kk;
      float4 v = *(const float4*)src;
      half4 o = { (_Float16)v.x, (_Float16)v.y, (_Float16)v.z, (_Float16)v.w };
      *(half4*)(Acat + (size_t)m * DMODEL + kk) = o;
    }
    return;
  }
  const float* in; _Float16* out; int C;
  if (z == 0)      { in = Wqkv; out = WqkvT; C = 3072; }
  else if (z == 1) { if (blockIdx.x >= 16) return; in = Wr; out = WrT; C = 1024; }
  else             { if (blockIdx.x >= 16) return; in = Wo; out = WoT; C = 1024; }
  const int R = 1024;
  int c0 = blockIdx.x * 64, r0 = blockIdx.y * 64;
#pragma unroll
  for (int u = 0; u < 16; ++u) {
    int lin = u * 256 + tid;
    int rr = lin >> 6, cc = lin & 63;
    T[rr][cc] = in[(size_t)(r0 + rr) * C + c0 + cc];
  }
  __syncthreads();
#pragma unroll
  for (int u = 0; u < 16; ++u) {
    int lin = u * 256 + tid;
    int cc = lin >> 6, rr = lin & 63;
    out[(size_t)(c0 + cc) * R + r0 + rr] = (_Float16)T[rr][cc];
  }
}

// per (b,h): V [2048][64] -> V^T [64][2048]
__global__ __launch_bounds__(256) void k_trans_v(const _Float16* __restrict__ Vb,
                                                 _Float16* __restrict__ VbT)
{
  __shared__ _Float16 T[64][72];
  int r0 = blockIdx.x * 64;
  int bh = blockIdx.y;
  const _Float16* in = Vb + (size_t)bh * KLEN * DHEAD;
  _Float16* out = VbT + (size_t)bh * DHEAD * KLEN;
  int tid = threadIdx.x;
#pragma unroll
  for (int u = 0; u < 16; ++u) {
    int lin = u * 256 + tid;
    int rr = lin >> 6, cc = lin & 63;
    T[rr][cc] = in[(size_t)(r0 + rr) * DHEAD + cc];
  }
  __syncthreads();
#pragma unroll
  for (int u = 0; u < 16; ++u) {
    int lin = u * 256 + tid;
    int cc = lin >> 6, rr = lin & 63;
    out[(size_t)cc * KLEN + r0 + rr] = T[rr][cc];
  }
}

// ---------------------------------------------------------------------------
// 128x128 MFMA GEMM core, async global->LDS staging; shared mem passed in.
// ---------------------------------------------------------------------------
template<typename Epi>
__device__ __forceinline__ void gemm_tile_128(const _Float16* __restrict__ A,
                                              const _Float16* __restrict__ B,
                                              int K, int m0, int n0,
                                              _Float16* As, _Float16* Bs, Epi epi)
{
  const int tid = threadIdx.x;
  const int lane = tid & 63;
  const int wave = tid >> 6;
  const int q = lane >> 4, l16 = lane & 15;
  const int wm = wave >> 1, wn = wave & 1;
  f32x4 acc[4][4] = {};

  for (int k0 = 0; k0 < K; k0 += 32) {
    __syncthreads();
#pragma unroll
    for (int i = 0; i < 2; ++i) {
      int c = i * 256 + tid;
      int row = c >> 2, pos = c & 3;
      int col8 = pos ^ ((row >> 1) & 3);
      gll16(&As[c * 8], A + (size_t)(m0 + row) * K + k0 + col8 * 8);
      gll16(&Bs[c * 8], B + (size_t)(n0 + row) * K + k0 + col8 * 8);
    }
    __syncthreads();
    half8 a[4], b[4];
#pragma unroll
    for (int rt = 0; rt < 4; ++rt) {
      int row = wm * 64 + rt * 16 + l16;
      a[rt] = *(const half8*)&As[(row * 4 + (q ^ ((row >> 1) & 3))) * 8];
    }
#pragma unroll
    for (int ct = 0; ct < 4; ++ct) {
      int row = wn * 64 + ct * 16 + l16;
      b[ct] = *(const half8*)&Bs[(row * 4 + (q ^ ((row >> 1) & 3))) * 8];
    }
#pragma unroll
    for (int rt = 0; rt < 4; ++rt)
#pragma unroll
      for (int ct = 0; ct < 4; ++ct)
        acc[rt][ct] = __builtin_amdgcn_mfma_f32_16x16x32_f16(a[rt], b[ct], acc[rt][ct], 0, 0, 0);
  }
#pragma unroll
  for (int rt = 0; rt < 4; ++rt)
#pragma unroll
    for (int ct = 0; ct < 4; ++ct)
#pragma unroll
      for (int reg = 0; reg < 4; ++reg) {
        int m = m0 + wm * 64 + rt * 16 + q * 4 + reg;
        int nn = n0 + wn * 64 + ct * 16 + l16;
        epi(m, nn, acc[rt][ct][reg]);
      }
}

// GEMM1+2 merged: by<64 -> cat@W_qkv scatter epilogue; by>=64 -> RelP@WrT -> Rk2
__global__ __launch_bounds__(256, 2) void k_gemm_qkv_rk(
    const _Float16* __restrict__ A, const _Float16* __restrict__ B,
    const _Float16* __restrict__ RelP, const _Float16* __restrict__ WrT,
    _Float16* __restrict__ Qw, _Float16* __restrict__ Qr,
    _Float16* __restrict__ Kb, _Float16* __restrict__ Vb,
    _Float16* __restrict__ Rk2,
    const float* __restrict__ rwb, const float* __restrict__ rrb)
{
  __shared__ __align__(16) _Float16 As[128 * 32];
  __shared__ __align__(16) _Float16 Bs[128 * 32];
  const int bx = blockIdx.x, by = blockIdx.y;
  if (by >= 64) {                                  // rk tiles
    if (bx >= 8) return;
    gemm_tile_128(RelP, WrT, DMODEL, (by - 64) * 128, bx * 128, As, Bs,
      [=](int m, int nn, float v) {
        int hh = nn >> 6, dd = nn & 63;
        Rk2[((size_t)hh * KLEN + m) * DHEAD + dd] = (_Float16)v;
      });
    return;
  }
  if (bx < 8 && by < 32) return;                   // q-section for mem rows unused
  const int sec = bx >> 3;                          // uniform per block
  gemm_tile_128(A, B, DMODEL, by * 128, bx * 128, As, Bs,
    [=](int m, int nn, float v) {
      int c = nn & 1023;
      int hh = c >> 6, dd = c & 63;
      int crow = m >> 2, bb = m & 3;
      int bhh = bb * NHEAD + hh;
      if (sec == 0) {
        int i = crow - MLEN;
        size_t o = ((size_t)bhh * QLEN + i) * DHEAD + dd;
        Qw[o] = (_Float16)((v + rwb[c]) * QSCALE);
        Qr[o] = (_Float16)((v + rrb[c]) * QSCALE);
      } else if (sec == 1) {
        Kb[((size_t)bhh * KLEN + crow) * DHEAD + dd] = (_Float16)v;
      } else {
        Vb[((size_t)bhh * KLEN + crow) * DHEAD + dd] = (_Float16)v;
      }
    });
}

// GEMM3: attn_vec @ W_o + content -> Y (fp32)
__global__ __launch_bounds__(256, 2) void k_gemm_out(
    const _Float16* __restrict__ A, const _Float16* __restrict__ B,
    const float* __restrict__ content, float* __restrict__ Y)
{
  __shared__ __align__(16) _Float16 As[128 * 32];
  __shared__ __align__(16) _Float16 Bs[128 * 32];
  gemm_tile_128(A, B, DMODEL, blockIdx.y * 128, blockIdx.x * 128, As, Bs,
    [=](int m, int nn, float v) {
      Y[(size_t)m * DMODEL + nn] = v + content[(size_t)m * DMODEL + nn];
    });
}

// ---------------------------------------------------------------------------
// Flash attention w/ XL relative shift. 64-row Q-blocks, 1 row-group/wave.
//  - all 10 r_k loads issued up-front per tile; (256,3) gives the allocator
//    ~170 VGPRs so they stay register-resident (round 5's (256,4) spilled)
//  - max-free online softmax (pre-scaled scores, exp2; |s| bounded)
//  - rel-shift via intra-16-group shuffles; boundary-split score loop
//  - double-buffered async K/V staging, one barrier per j-tile
// ---------------------------------------------------------------------------
__global__ __launch_bounds__(256, 3) void k_attn(
    const _Float16* __restrict__ Qw, const _Float16* __restrict__ Qr,
    const _Float16* __restrict__ Kb, const _Float16* __restrict__ VbT,
    const _Float16* __restrict__ Rk2, _Float16* __restrict__ AV)
{
  __shared__ __align__(16) _Float16 Kl[2][64 * 64];     // [j][d], chunk-swizzled
  __shared__ __align__(16) _Float16 Vtl[2][64 * 64];    // [d][j], chunk-swizzled
  __shared__ __align__(16) _Float16 Pl[4][16 * 64];     // per-wave P

  const int tid = threadIdx.x;
  const int lane = tid & 63, wave = tid >> 6;
  const int q = lane >> 4, l16 = lane & 15;
  const int i0 = (15 - blockIdx.x) * 64;                // longest blocks first
  const int bh = blockIdx.y;
  const int h = bh & 15, bb = bh >> 4;

  const _Float16* Qwb = Qw + (size_t)bh * QLEN * DHEAD;
  const _Float16* Qrb = Qr + (size_t)bh * QLEN * DHEAD;
  const _Float16* Kbb = Kb + (size_t)bh * KLEN * DHEAD;
  const _Float16* Vtb = VbT + (size_t)bh * DHEAD * KLEN;
  const _Float16* Rkb = Rk2 + (size_t)h * KLEN * DHEAD;

  const int iw = i0 + wave * 16;
  const int lim = iw + 15 + MLEN;

  half8 aqw[2], aqr[2];
#pragma unroll
  for (int s = 0; s < 2; ++s) {
    size_t o = (size_t)(iw + l16) * DHEAD + s * 32 + q * 8;
    aqw[s] = *(const half8*)(Qwb + o);
    aqr[s] = *(const half8*)(Qrb + o);
  }

  f32x4 oa[4] = {};
  float l_lane[4] = {};
  _Float16* Plw = &Pl[wave][0];

  auto stage = [&](int j0s, int bufi) {
#pragma unroll
    for (int i = 0; i < 2; ++i) {
      int c = i * 256 + tid;
      int row = c >> 3;
      int col8 = (c & 7) ^ (row & 7);
      gll16(&Kl[bufi][c * 8],  Kbb + (size_t)(j0s + row) * DHEAD + col8 * 8);
      gll16(&Vtl[bufi][c * 8], Vtb + (size_t)row * KLEN + j0s + col8 * 8);
    }
  };

  const int n_jt = (i0 >> 6) + 17;
  stage(0, 0);
  for (int jt = 0; jt < n_jt; ++jt) {
    const int j0 = jt * 64;
    const int bufi = jt & 1;
    __syncthreads();                              // publish buf[bufi], free other

    const bool act = (j0 <= lim);
    // all 10 r_k loads for THIS tile, issued before staging + AC
    half8 rk[5][2];
    if (act) {
      const int rs = j0 - iw + 1008;
#pragma unroll
      for (int rt = 0; rt < 5; ++rt) {
        int r = rs + rt * 16 + l16;
        int rc = r < 0 ? 0 : (r > KLEN - 1 ? KLEN - 1 : r);  // clamped rows
        const _Float16* base = Rkb + (size_t)rc * DHEAD + q * 8;  // feed only
        rk[rt][0] = *(const half8*)(base);                        // masked cols
        rk[rt][1] = *(const half8*)(base + 32);
      }
    }
    if (jt + 1 < n_jt) stage((jt + 1) * 64, bufi ^ 1);
    if (!act) continue;                           // fully masked for this wave

    const _Float16* Klb = Kl[bufi];
    const _Float16* Vtlb = Vtl[bufi];

    // AC: Qw @ K^T from LDS (covers rk load latency)
    f32x4 ac[4] = {};
#pragma unroll
    for (int ct = 0; ct < 4; ++ct) {
      int row = ct * 16 + l16;
#pragma unroll
      for (int s = 0; s < 2; ++s) {
        int pos = (s * 4 + q) ^ (row & 7);
        half8 bk = *(const half8*)&Klb[(row * 8 + pos) * 8];
        ac[ct] = __builtin_amdgcn_mfma_f32_16x16x32_f16(aqw[s], bk, ac[ct], 0, 0, 0);
      }
    }

    // BD: Qr @ r_k_window^T (data already resident)
    f32x4 bd[5] = {};
#pragma unroll
    for (int rt = 0; rt < 5; ++rt) {
      bd[rt] = __builtin_amdgcn_mfma_f32_16x16x32_f16(aqr[0], rk[rt][0], bd[rt], 0, 0, 0);
      bd[rt] = __builtin_amdgcn_mfma_f32_16x16x32_f16(aqr[1], rk[rt][1], bd[rt], 0, 0, 0);
    }

    // score: shuffle rel-shift + exp2 -> Pl; boundary-split (wave-uniform)
    const bool boundary = (j0 + 63 > iw + MLEN);
#pragma unroll
    for (int reg = 0; reg < 4; ++reg) {
      const int m = q * 4 + reg;                  // uniform within 16-group
      const int src = (l16 + 15 - m) & 15;
      float sh[5];
#pragma unroll
      for (int rt = 0; rt < 5; ++rt) sh[rt] = __shfl(bd[rt][reg], src, 16);
      const bool sel = (l16 > m);
      float acc = 0.f;
      if (!boundary) {
#pragma unroll
        for (int ct = 0; ct < 4; ++ct) {
          float bdv = sel ? sh[ct + 1] : sh[ct];
          float e = __builtin_amdgcn_exp2f(ac[ct][reg] + bdv);
          acc += e;
          int c = ct * 16 + l16;
          Plw[m * 64 + (((c >> 3) ^ (m & 7)) * 8) + (c & 7)] = (_Float16)e;
        }
      } else {
#pragma unroll
        for (int ct = 0; ct < 4; ++ct) {
          float bdv = sel ? sh[ct + 1] : sh[ct];
          float sv = ac[ct][reg] + bdv;
          if (j0 + ct * 16 + l16 > iw + m + MLEN) sv = NEG_INF;
          float e = __builtin_amdgcn_exp2f(sv);
          acc += e;
          int c = ct * 16 + l16;
          Plw[m * 64 + (((c >> 3) ^ (m & 7)) * 8) + (c & 7)] = (_Float16)e;
        }
      }
      l_lane[reg] += acc;
    }

    // PV: O += P @ V
    half8 ap[2];
#pragma unroll
    for (int s = 0; s < 2; ++s)
      ap[s] = *(const half8*)&Plw[l16 * 64 + (((s * 4 + q) ^ (l16 & 7)) * 8)];
#pragma unroll
    for (int t = 0; t < 4; ++t) {
      int row = t * 16 + l16;
#pragma unroll
      for (int s = 0; s < 2; ++s) {
        int pos = (s * 4 + q) ^ (row & 7);
        half8 bv = *(const half8*)&Vtlb[(row * 8 + pos) * 8];
        oa[t] = __builtin_amdgcn_mfma_f32_16x16x32_f16(ap[s], bv, oa[t], 0, 0, 0);
      }
    }
  }

  float linv[4];
#pragma unroll
  for (int reg = 0; reg < 4; ++reg) {
    float v = l_lane[reg];
    v += __shfl_xor(v, 1, 16);
    v += __shfl_xor(v, 2, 16);
    v += __shfl_xor(v, 4, 16);
    v += __shfl_xor(v, 8, 16);
    linv[reg] = 1.0f / v;
  }
#pragma unroll
  for (int t = 0; t < 4; ++t)
#pragma unroll
    for (int reg = 0; reg < 4; ++reg) {
      int ii = iw + q * 4 + reg;
      AV[(size_t)(ii * BATCH + bb) * DMODEL + h * DHEAD + t * 16 + l16] =
          (_Float16)(oa[t][reg] * linv[reg]);
    }
}

// ---------------------------------------------------------------------------
__global__ __launch_bounds__(256) void k_ln(const float* __restrict__ Y,
                                            const float* __restrict__ gamma,
                                            const float* __restrict__ beta,
                                            float* __restrict__ out)
{
  int row = blockIdx.x, tid = threadIdx.x;
  const float4 v = ((const float4*)(Y + (size_t)row * DMODEL))[tid];
  float s = v.x + v.y + v.z + v.w;
  float ss = v.x * v.x + v.y * v.y + v.z * v.z + v.w * v.w;
#pragma unroll
  for (int off = 32; off >= 1; off >>= 1) {
    s += __shfl_xor(s, off, 64);
    ss += __shfl_xor(ss, off, 64);
  }
  __shared__ float red[8];
  int wave = tid >> 6, lane = tid & 63;
  if (lane == 0) { red[wave] = s; red[4 + wave] = ss; }
  __syncthreads();
  s = red[0] + red[1] + red[2] + red[3];
  ss = red[4] + red[5] + red[6] + red[7];
  float mu = s * (1.0f / DMODEL);
  float var = ss * (1.0f / DMODEL) - mu * mu;
  float rstd = rsqrtf(var + 1e-5f);
  const float4 g = ((const float4*)gamma)[tid];
  const float4 bt = ((const float4*)beta)[tid];
  float4 o;
  o.x = (v.x - mu) * rstd * g.x + bt.x;
  o.y = (v.y - mu) * rstd * g.y + bt.y;
  o.z = (v.z - mu) * rstd * g.z + bt.z;
  o.w = (v.w - mu) * rstd * g.w + bt.w;
  ((float4*)(out + (size_t)row * DMODEL))[tid] = o;
}

// ---------------------------------------------------------------------------
extern "C" void kernel_launch(void* const* d_in, const int* in_sizes, int n_in,
                              void* d_out, int out_size, void* d_ws, size_t ws_size,
                              hipStream_t stream)
{
  (void)in_sizes; (void)n_in; (void)out_size; (void)ws_size;
  const float* content = (const float*)d_in[0];
  const float* rel_pos = (const float*)d_in[1];
  const float* mems    = (const float*)d_in[2];
  const float* rwb     = (const float*)d_in[3];
  const float* rrb     = (const float*)d_in[4];
  const float* Wqkv    = (const float*)d_in[5];
  const float* Wr      = (const float*)d_in[6];
  const float* Wo      = (const float*)d_in[7];
  const float* gamma   = (const float*)d_in[8];
  const float* beta    = (const float*)d_in[9];

  char* ws = (char*)d_ws;
  size_t off = 0;
  auto take = [&](size_t bytes) { char* p = ws + off; off += (bytes + 255) & ~(size_t)255; return p; };

  _Float16* Acat  = (_Float16*)take(8192ull * 1024 * 2);      // reused as VbT
  _Float16* WqkvT = (_Float16*)take(3072ull * 1024 * 2);
  _Float16* RelP  = (_Float16*)take(2048ull * 1024 * 2);
  _Float16* WrT   = (_Float16*)take(1024ull * 1024 * 2);
  _Float16* WoT   = (_Float16*)take(1024ull * 1024 * 2);
  _Float16* Qw    = (_Float16*)take(64ull * 1024 * 64 * 2);
  _Float16* Qr    = (_Float16*)take(64ull * 1024 * 64 * 2);
  _Float16* Kb    = (_Float16*)take(64ull * 2048 * 64 * 2);   // reused as Y (fp32)
  _Float16* Vb    = (_Float16*)take(64ull * 2048 * 64 * 2);
  _Float16* AV    = (_Float16*)take(4096ull * 1024 * 2);
  _Float16* Rk2   = (_Float16*)take(16ull * 2048 * 64 * 2);
  _Float16* VbT   = Acat;   // Acat dead after k_gemm_qkv_rk
  float*    Y     = (float*)Kb;  // Kb dead after k_attn
  float*    out   = (float*)d_out;

  k_prep<<<dim3(48, 16, 5), dim3(256), 0, stream>>>(Wqkv, Wr, Wo, rel_pos, mems, content,
                                                    WqkvT, WrT, WoT, RelP, Acat);
  k_gemm_qkv_rk<<<dim3(24, 80), dim3(256), 0, stream>>>(Acat, WqkvT, RelP, WrT,
                                                        Qw, Qr, Kb, Vb, Rk2, rwb, rrb);
  k_trans_v<<<dim3(32, 64), dim3(256), 0, stream>>>(Vb, VbT);
  k_attn<<<dim3(16, 64), dim3(256), 0, stream>>>(Qw, Qr, Kb, VbT, Rk2, AV);
  k_gemm_out<<<dim3(8, 32), dim3(256), 0, stream>>>(AV, WoT, content, Y);
  k_ln<<<dim3(4096), dim3(256), 0, stream>>>(Y, gamma, beta, out);
}

// Round 7
// 395.202 us; speedup vs baseline: 1.4751x; 1.1407x over previous
//
#include <hip/hip_runtime.h>

#define QLEN 1024
#define MLEN 1024
#define KLEN 2048
#define BATCH 4
#define NHEAD 16
#define DHEAD 64
#define DMODEL 1024

typedef _Float16 half8 __attribute__((ext_vector_type(8)));
typedef _Float16 half4 __attribute__((ext_vector_type(4)));
typedef float f32x4 __attribute__((ext_vector_type(4)));

#define NEG_INF (-__builtin_inff())
#define QSCALE 0.18033688011112042f /* 0.125 * log2(e) */

typedef __attribute__((address_space(3))) unsigned int lds_u32;
typedef __attribute__((address_space(1))) unsigned int glb_u32;

__device__ __forceinline__ void gll16(void* lds, const void* g) {
  __builtin_amdgcn_global_load_lds((const glb_u32*)g, (lds_u32*)lds, 16, 0, 0);
}

// ---------------------------------------------------------------------------
// Merged prep:
//   z=0 WqkvT, z=1 WrT, z=2 WoT (fp32->f16 64x64 transposes)
//   z=3 conv rel_pos->RelP (grid-stride), z=4 pack [mems;content]->Acat
// ---------------------------------------------------------------------------
__global__ __launch_bounds__(256) void k_prep(const float* __restrict__ Wqkv,
                                              const float* __restrict__ Wr,
                                              const float* __restrict__ Wo,
                                              const float* __restrict__ rel_pos,
                                              const float* __restrict__ mems,
                                              const float* __restrict__ content,
                                              _Float16* __restrict__ WqkvT,
                                              _Float16* __restrict__ WrT,
                                              _Float16* __restrict__ WoT,
                                              _Float16* __restrict__ RelP,
                                              _Float16* __restrict__ Acat)
{
  __shared__ float T[64][65];
  const int z = blockIdx.z;
  const int tid = threadIdx.x;
  if (z == 3) {
    int nb = gridDim.x * gridDim.y;
    int bid = blockIdx.y * gridDim.x + blockIdx.x;
    for (int e = (bid * 256 + tid) * 4; e < KLEN * DMODEL; e += nb * 256 * 4) {
      float4 v = *(const float4*)(rel_pos + e);
      half4 o = { (_Float16)v.x, (_Float16)v.y, (_Float16)v.z, (_Float16)v.w };
      *(half4*)(RelP + e) = o;
    }
    return;
  }
  if (z == 4) {
    int nb = gridDim.x * gridDim.y;
    int bid = blockIdx.y * gridDim.x + blockIdx.x;
    for (int e = (bid * 256 + tid) * 4; e < 8192 * DMODEL; e += nb * 256 * 4) {
      int m = e >> 10, kk = e & 1023;
      int crow = m >> 2, bb = m & 3;
      const float* src;
      if (crow < MLEN) src = mems + (size_t)(crow * BATCH + bb) * DMODEL + kk;
      else             src = content + (size_t)((crow - MLEN) * BATCH + bb) * DMODEL + kk;
      float4 v = *(const float4*)src;
      half4 o = { (_Float16)v.x, (_Float16)v.y, (_Float16)v.z, (_Float16)v.w };
      *(half4*)(Acat + (size_t)m * DMODEL + kk) = o;
    }
    return;
  }
  const float* in; _Float16* out; int C;
  if (z == 0)      { in = Wqkv; out = WqkvT; C = 3072; }
  else if (z == 1) { if (blockIdx.x >= 16) return; in = Wr; out = WrT; C = 1024; }
  else             { if (blockIdx.x >= 16) return; in = Wo; out = WoT; C = 1024; }
  const int R = 1024;
  int c0 = blockIdx.x * 64, r0 = blockIdx.y * 64;
#pragma unroll
  for (int u = 0; u < 16; ++u) {
    int lin = u * 256 + tid;
    int rr = lin >> 6, cc = lin & 63;
    T[rr][cc] = in[(size_t)(r0 + rr) * C + c0 + cc];
  }
  __syncthreads();
#pragma unroll
  for (int u = 0; u < 16; ++u) {
    int lin = u * 256 + tid;
    int cc = lin >> 6, rr = lin & 63;
    out[(size_t)(c0 + cc) * R + r0 + rr] = (_Float16)T[rr][cc];
  }
}

// per (b,h): V [2048][64] -> V^T [64][2048]
__global__ __launch_bounds__(256) void k_trans_v(const _Float16* __restrict__ Vb,
                                                 _Float16* __restrict__ VbT)
{
  __shared__ _Float16 T[64][72];
  int r0 = blockIdx.x * 64;
  int bh = blockIdx.y;
  const _Float16* in = Vb + (size_t)bh * KLEN * DHEAD;
  _Float16* out = VbT + (size_t)bh * DHEAD * KLEN;
  int tid = threadIdx.x;
#pragma unroll
  for (int u = 0; u < 16; ++u) {
    int lin = u * 256 + tid;
    int rr = lin >> 6, cc = lin & 63;
    T[rr][cc] = in[(size_t)(r0 + rr) * DHEAD + cc];
  }
  __syncthreads();
#pragma unroll
  for (int u = 0; u < 16; ++u) {
    int lin = u * 256 + tid;
    int cc = lin >> 6, rr = lin & 63;
    out[(size_t)cc * KLEN + r0 + rr] = T[rr][cc];
  }
}

// ---------------------------------------------------------------------------
// 128x128 MFMA GEMM core, async global->LDS staging; shared mem passed in.
// ---------------------------------------------------------------------------
template<typename Epi>
__device__ __forceinline__ void gemm_tile_128(const _Float16* __restrict__ A,
                                              const _Float16* __restrict__ B,
                                              int K, int m0, int n0,
                                              _Float16* As, _Float16* Bs, Epi epi)
{
  const int tid = threadIdx.x;
  const int lane = tid & 63;
  const int wave = tid >> 6;
  const int q = lane >> 4, l16 = lane & 15;
  const int wm = wave >> 1, wn = wave & 1;
  f32x4 acc[4][4] = {};

  for (int k0 = 0; k0 < K; k0 += 32) {
    __syncthreads();
#pragma unroll
    for (int i = 0; i < 2; ++i) {
      int c = i * 256 + tid;
      int row = c >> 2, pos = c & 3;
      int col8 = pos ^ ((row >> 1) & 3);
      gll16(&As[c * 8], A + (size_t)(m0 + row) * K + k0 + col8 * 8);
      gll16(&Bs[c * 8], B + (size_t)(n0 + row) * K + k0 + col8 * 8);
    }
    __syncthreads();
    half8 a[4], b[4];
#pragma unroll
    for (int rt = 0; rt < 4; ++rt) {
      int row = wm * 64 + rt * 16 + l16;
      a[rt] = *(const half8*)&As[(row * 4 + (q ^ ((row >> 1) & 3))) * 8];
    }
#pragma unroll
    for (int ct = 0; ct < 4; ++ct) {
      int row = wn * 64 + ct * 16 + l16;
      b[ct] = *(const half8*)&Bs[(row * 4 + (q ^ ((row >> 1) & 3))) * 8];
    }
#pragma unroll
    for (int rt = 0; rt < 4; ++rt)
#pragma unroll
      for (int ct = 0; ct < 4; ++ct)
        acc[rt][ct] = __builtin_amdgcn_mfma_f32_16x16x32_f16(a[rt], b[ct], acc[rt][ct], 0, 0, 0);
  }
#pragma unroll
  for (int rt = 0; rt < 4; ++rt)
#pragma unroll
    for (int ct = 0; ct < 4; ++ct)
#pragma unroll
      for (int reg = 0; reg < 4; ++reg) {
        int m = m0 + wm * 64 + rt * 16 + q * 4 + reg;
        int nn = n0 + wn * 64 + ct * 16 + l16;
        epi(m, nn, acc[rt][ct][reg]);
      }
}

// GEMM1+2 merged: by<64 -> cat@W_qkv scatter epilogue; by>=64 -> RelP@WrT -> Rk2
__global__ __launch_bounds__(256, 2) void k_gemm_qkv_rk(
    const _Float16* __restrict__ A, const _Float16* __restrict__ B,
    const _Float16* __restrict__ RelP, const _Float16* __restrict__ WrT,
    _Float16* __restrict__ Qw, _Float16* __restrict__ Qr,
    _Float16* __restrict__ Kb, _Float16* __restrict__ Vb,
    _Float16* __restrict__ Rk2,
    const float* __restrict__ rwb, const float* __restrict__ rrb)
{
  __shared__ __align__(16) _Float16 As[128 * 32];
  __shared__ __align__(16) _Float16 Bs[128 * 32];
  const int bx = blockIdx.x, by = blockIdx.y;
  if (by >= 64) {                                  // rk tiles
    if (bx >= 8) return;
    gemm_tile_128(RelP, WrT, DMODEL, (by - 64) * 128, bx * 128, As, Bs,
      [=](int m, int nn, float v) {
        int hh = nn >> 6, dd = nn & 63;
        Rk2[((size_t)hh * KLEN + m) * DHEAD + dd] = (_Float16)v;
      });
    return;
  }
  if (bx < 8 && by < 32) return;                   // q-section for mem rows unused
  const int sec = bx >> 3;                          // uniform per block
  gemm_tile_128(A, B, DMODEL, by * 128, bx * 128, As, Bs,
    [=](int m, int nn, float v) {
      int c = nn & 1023;
      int hh = c >> 6, dd = c & 63;
      int crow = m >> 2, bb = m & 3;
      int bhh = bb * NHEAD + hh;
      if (sec == 0) {
        int i = crow - MLEN;
        size_t o = ((size_t)bhh * QLEN + i) * DHEAD + dd;
        Qw[o] = (_Float16)((v + rwb[c]) * QSCALE);
        Qr[o] = (_Float16)((v + rrb[c]) * QSCALE);
      } else if (sec == 1) {
        Kb[((size_t)bhh * KLEN + crow) * DHEAD + dd] = (_Float16)v;
      } else {
        Vb[((size_t)bhh * KLEN + crow) * DHEAD + dd] = (_Float16)v;
      }
    });
}

// GEMM3: attn_vec @ W_o + content -> Y (fp32)
__global__ __launch_bounds__(256, 2) void k_gemm_out(
    const _Float16* __restrict__ A, const _Float16* __restrict__ B,
    const float* __restrict__ content, float* __restrict__ Y)
{
  __shared__ __align__(16) _Float16 As[128 * 32];
  __shared__ __align__(16) _Float16 Bs[128 * 32];
  gemm_tile_128(A, B, DMODEL, blockIdx.y * 128, blockIdx.x * 128, As, Bs,
    [=](int m, int nn, float v) {
      Y[(size_t)m * DMODEL + nn] = v + content[(size_t)m * DMODEL + nn];
    });
}

// ---------------------------------------------------------------------------
// Flash attention w/ XL relative shift — SOFTWARE-PIPELINED K-loop.
// Per iteration: AC(jt+1) MFMAs overlap score(jt) VALU/DS; BD(jt+1) at end
// consumes rk loads issued mid-body. K staged 2 tiles ahead, V 1 tile ahead
// (staggered double buffers), so every staged load has a full iteration
// before its barrier drain. 1D grid, bh-fastest: all 16 q-blocks of one bh
// land on XCD bh%8 (K/V L2 locality); longest q-blocks dispatch first.
// ---------------------------------------------------------------------------
__global__ __launch_bounds__(256, 2) void k_attn(
    const _Float16* __restrict__ Qw, const _Float16* __restrict__ Qr,
    const _Float16* __restrict__ Kb, const _Float16* __restrict__ VbT,
    const _Float16* __restrict__ Rk2, _Float16* __restrict__ AV)
{
  __shared__ __align__(16) _Float16 Kl[2][64 * 64];     // [j][d], chunk-swizzled
  __shared__ __align__(16) _Float16 Vtl[2][64 * 64];    // [d][j], chunk-swizzled
  __shared__ __align__(16) _Float16 Pl[4][16 * 64];     // per-wave P

  const int tid = threadIdx.x;
  const int lane = tid & 63, wave = tid >> 6;
  const int q = lane >> 4, l16 = lane & 15;
  const int bh = blockIdx.x & 63;                       // XCD = bh % 8
  const int xq = blockIdx.x >> 6;
  const int i0 = (15 - xq) * 64;                        // longest first
  const int h = bh & 15, bb = bh >> 4;

  const _Float16* Qwb = Qw + (size_t)bh * QLEN * DHEAD;
  const _Float16* Qrb = Qr + (size_t)bh * QLEN * DHEAD;
  const _Float16* Kbb = Kb + (size_t)bh * KLEN * DHEAD;
  const _Float16* Vtb = VbT + (size_t)bh * DHEAD * KLEN;
  const _Float16* Rkb = Rk2 + (size_t)h * KLEN * DHEAD;

  const int iw = i0 + wave * 16;
  const int lim = iw + 15 + MLEN;

  half8 aqw[2], aqr[2];
#pragma unroll
  for (int s = 0; s < 2; ++s) {
    size_t o = (size_t)(iw + l16) * DHEAD + s * 32 + q * 8;
    aqw[s] = *(const half8*)(Qwb + o);
    aqr[s] = *(const half8*)(Qrb + o);
  }

  f32x4 oa[4] = {};
  float l_lane[4] = {};
  _Float16* Plw = &Pl[wave][0];

  auto stageK = [&](int j0s, int bufi) {
#pragma unroll
    for (int i = 0; i < 2; ++i) {
      int c = i * 256 + tid;
      int row = c >> 3;
      int col8 = (c & 7) ^ (row & 7);
      gll16(&Kl[bufi][c * 8], Kbb + (size_t)(j0s + row) * DHEAD + col8 * 8);
    }
  };
  auto stageV = [&](int j0s, int bufi) {
#pragma unroll
    for (int i = 0; i < 2; ++i) {
      int c = i * 256 + tid;
      int row = c >> 3;
      int col8 = (c & 7) ^ (row & 7);
      gll16(&Vtl[bufi][c * 8], Vtb + (size_t)row * KLEN + j0s + col8 * 8);
    }
  };
  auto loadRK = [&](int j0t, half8 (&rk)[5][2]) {
    const int rs = j0t - iw + 1008;
#pragma unroll
    for (int rt = 0; rt < 5; ++rt) {
      int r = rs + rt * 16 + l16;
      int rc = r < 0 ? 0 : (r > KLEN - 1 ? KLEN - 1 : r);     // clamped rows
      const _Float16* base = Rkb + (size_t)rc * DHEAD + q * 8; // feed only
      rk[rt][0] = *(const half8*)(base);                       // masked cols
      rk[rt][1] = *(const half8*)(base + 32);
    }
  };
  auto computeAC = [&](const _Float16* Klb, f32x4 (&ac)[4]) {
#pragma unroll
    for (int ct = 0; ct < 4; ++ct) {
      int row = ct * 16 + l16;
#pragma unroll
      for (int s = 0; s < 2; ++s) {
        int pos = (s * 4 + q) ^ (row & 7);
        half8 bk = *(const half8*)&Klb[(row * 8 + pos) * 8];
        ac[ct] = __builtin_amdgcn_mfma_f32_16x16x32_f16(aqw[s], bk, ac[ct], 0, 0, 0);
      }
    }
  };
  auto computeBD = [&](half8 (&rk)[5][2], f32x4 (&bd)[5]) {
#pragma unroll
    for (int rt = 0; rt < 5; ++rt) {
      bd[rt] = __builtin_amdgcn_mfma_f32_16x16x32_f16(aqr[0], rk[rt][0], bd[rt], 0, 0, 0);
      bd[rt] = __builtin_amdgcn_mfma_f32_16x16x32_f16(aqr[1], rk[rt][1], bd[rt], 0, 0, 0);
    }
  };

  const int n_jt = (i0 >> 6) + 17;

  // prologue: stage K0,V0; publish; stage K1; compute AC(0), BD(0)
  stageK(0, 0);
  stageV(0, 0);
  __syncthreads();
  stageK(64, 1);
  f32x4 ac_p[4] = {}, bd_p[5] = {};
  {
    half8 rk0[5][2];
    loadRK(0, rk0);
    computeAC(Kl[0], ac_p);
    computeBD(rk0, bd_p);
  }

  for (int jt = 0; jt < n_jt; ++jt) {
    const int j0 = jt * 64;
    __syncthreads();                       // publish K(jt+1), V(jt)
    if (jt + 2 < n_jt) stageK((jt + 2) * 64, jt & 1);
    if (jt + 1 < n_jt) stageV((jt + 1) * 64, (jt + 1) & 1);

    const bool act  = (j0 <= lim);
    const bool actn = (j0 + 64 <= lim) && (jt + 1 < n_jt);

    // AC for NEXT tile (MFMA pipe) — overlaps this tile's score (VALU/DS)
    f32x4 ac_n[4] = {};
    if (actn) computeAC(Kl[(jt + 1) & 1], ac_n);

    if (act) {
      // score(jt): shuffle rel-shift + exp2 -> Pl (per-wave, no barrier)
      const bool boundary = (j0 + 63 > iw + MLEN);
#pragma unroll
      for (int reg = 0; reg < 4; ++reg) {
        const int m = q * 4 + reg;               // uniform within 16-group
        const int src = (l16 + 15 - m) & 15;
        float sh[5];
#pragma unroll
        for (int rt = 0; rt < 5; ++rt) sh[rt] = __shfl(bd_p[rt][reg], src, 16);
        const bool sel = (l16 > m);
        float acc = 0.f;
        if (!boundary) {
#pragma unroll
          for (int ct = 0; ct < 4; ++ct) {
            float bdv = sel ? sh[ct + 1] : sh[ct];
            float e = __builtin_amdgcn_exp2f(ac_p[ct][reg] + bdv);
            acc += e;
            int c = ct * 16 + l16;
            Plw[m * 64 + (((c >> 3) ^ (m & 7)) * 8) + (c & 7)] = (_Float16)e;
          }
        } else {
#pragma unroll
          for (int ct = 0; ct < 4; ++ct) {
            float bdv = sel ? sh[ct + 1] : sh[ct];
            float sv = ac_p[ct][reg] + bdv;
            if (j0 + ct * 16 + l16 > iw + m + MLEN) sv = NEG_INF;
            float e = __builtin_amdgcn_exp2f(sv);
            acc += e;
            int c = ct * 16 + l16;
            Plw[m * 64 + (((c >> 3) ^ (m & 7)) * 8) + (c & 7)] = (_Float16)e;
          }
        }
        l_lane[reg] += acc;
      }
    }

    // rk for NEXT tile — covered by P round-trip + PV below
    half8 rk[5][2];
    if (actn) loadRK((jt + 1) * 64, rk);

    if (act) {
      // PV(jt): O += P @ V
      half8 ap[2];
#pragma unroll
      for (int s = 0; s < 2; ++s)
        ap[s] = *(const half8*)&Plw[l16 * 64 + (((s * 4 + q) ^ (l16 & 7)) * 8)];
      const _Float16* Vtlb = Vtl[jt & 1];
#pragma unroll
      for (int t = 0; t < 4; ++t) {
        int row = t * 16 + l16;
#pragma unroll
        for (int s = 0; s < 2; ++s) {
          int pos = (s * 4 + q) ^ (row & 7);
          half8 bv = *(const half8*)&Vtlb[(row * 8 + pos) * 8];
          oa[t] = __builtin_amdgcn_mfma_f32_16x16x32_f16(ap[s], bv, oa[t], 0, 0, 0);
        }
      }
    }

    // BD for NEXT tile (MFMA, end of body)
    if (actn) {
#pragma unroll
      for (int rt = 0; rt < 5; ++rt) bd_p[rt] = f32x4{0.f, 0.f, 0.f, 0.f};
      computeBD(rk, bd_p);
    }
#pragma unroll
    for (int ct = 0; ct < 4; ++ct) ac_p[ct] = ac_n[ct];
  }

  float linv[4];
#pragma unroll
  for (int reg = 0; reg < 4; ++reg) {
    float v = l_lane[reg];
    v += __shfl_xor(v, 1, 16);
    v += __shfl_xor(v, 2, 16);
    v += __shfl_xor(v, 4, 16);
    v += __shfl_xor(v, 8, 16);
    linv[reg] = 1.0f / v;
  }
#pragma unroll
  for (int t = 0; t < 4; ++t)
#pragma unroll
    for (int reg = 0; reg < 4; ++reg) {
      int ii = iw + q * 4 + reg;
      AV[(size_t)(ii * BATCH + bb) * DMODEL + h * DHEAD + t * 16 + l16] =
          (_Float16)(oa[t][reg] * linv[reg]);
    }
}

// ---------------------------------------------------------------------------
__global__ __launch_bounds__(256) void k_ln(const float* __restrict__ Y,
                                            const float* __restrict__ gamma,
                                            const float* __restrict__ beta,
                                            float* __restrict__ out)
{
  int row = blockIdx.x, tid = threadIdx.x;
  const float4 v = ((const float4*)(Y + (size_t)row * DMODEL))[tid];
  float s = v.x + v.y + v.z + v.w;
  float ss = v.x * v.x + v.y * v.y + v.z * v.z + v.w * v.w;
#pragma unroll
  for (int off = 32; off >= 1; off >>= 1) {
    s += __shfl_xor(s, off, 64);
    ss += __shfl_xor(ss, off, 64);
  }
  __shared__ float red[8];
  int wave = tid >> 6, lane = tid & 63;
  if (lane == 0) { red[wave] = s; red[4 + wave] = ss; }
  __syncthreads();
  s = red[0] + red[1] + red[2] + red[3];
  ss = red[4] + red[5] + red[6] + red[7];
  float mu = s * (1.0f / DMODEL);
  float var = ss * (1.0f / DMODEL) - mu * mu;
  float rstd = rsqrtf(var + 1e-5f);
  const float4 g = ((const float4*)gamma)[tid];
  const float4 bt = ((const float4*)beta)[tid];
  float4 o;
  o.x = (v.x - mu) * rstd * g.x + bt.x;
  o.y = (v.y - mu) * rstd * g.y + bt.y;
  o.z = (v.z - mu) * rstd * g.z + bt.z;
  o.w = (v.w - mu) * rstd * g.w + bt.w;
  ((float4*)(out + (size_t)row * DMODEL))[tid] = o;
}

// ---------------------------------------------------------------------------
extern "C" void kernel_launch(void* const* d_in, const int* in_sizes, int n_in,
                              void* d_out, int out_size, void* d_ws, size_t ws_size,
                              hipStream_t stream)
{
  (void)in_sizes; (void)n_in; (void)out_size; (void)ws_size;
  const float* content = (const float*)d_in[0];
  const float* rel_pos = (const float*)d_in[1];
  const float* mems    = (const float*)d_in[2];
  const float* rwb     = (const float*)d_in[3];
  const float* rrb     = (const float*)d_in[4];
  const float* Wqkv    = (const float*)d_in[5];
  const float* Wr      = (const float*)d_in[6];
  const float* Wo      = (const float*)d_in[7];
  const float* gamma   = (const float*)d_in[8];
  const float* beta    = (const float*)d_in[9];

  char* ws = (char*)d_ws;
  size_t off = 0;
  auto take = [&](size_t bytes) { char* p = ws + off; off += (bytes + 255) & ~(size_t)255; return p; };

  _Float16* Acat  = (_Float16*)take(8192ull * 1024 * 2);      // reused as VbT
  _Float16* WqkvT = (_Float16*)take(3072ull * 1024 * 2);
  _Float16* RelP  = (_Float16*)take(2048ull * 1024 * 2);
  _Float16* WrT   = (_Float16*)take(1024ull * 1024 * 2);
  _Float16* WoT   = (_Float16*)take(1024ull * 1024 * 2);
  _Float16* Qw    = (_Float16*)take(64ull * 1024 * 64 * 2);
  _Float16* Qr    = (_Float16*)take(64ull * 1024 * 64 * 2);
  _Float16* Kb    = (_Float16*)take(64ull * 2048 * 64 * 2);   // reused as Y (fp32)
  _Float16* Vb    = (_Float16*)take(64ull * 2048 * 64 * 2);
  _Float16* AV    = (_Float16*)take(4096ull * 1024 * 2);
  _Float16* Rk2   = (_Float16*)take(16ull * 2048 * 64 * 2);
  _Float16* VbT   = Acat;   // Acat dead after k_gemm_qkv_rk
  float*    Y     = (float*)Kb;  // Kb dead after k_attn
  float*    out   = (float*)d_out;

  k_prep<<<dim3(48, 16, 5), dim3(256), 0, stream>>>(Wqkv, Wr, Wo, rel_pos, mems, content,
                                                    WqkvT, WrT, WoT, RelP, Acat);
  k_gemm_qkv_rk<<<dim3(24, 80), dim3(256), 0, stream>>>(Acat, WqkvT, RelP, WrT,
                                                        Qw, Qr, Kb, Vb, Rk2, rwb, rrb);
  k_trans_v<<<dim3(32, 64), dim3(256), 0, stream>>>(Vb, VbT);
  k_attn<<<dim3(1024), dim3(256), 0, stream>>>(Qw, Qr, Kb, VbT, Rk2, AV);
  k_gemm_out<<<dim3(8, 32), dim3(256), 0, stream>>>(AV, WoT, content, Y);
  k_ln<<<dim3(4096), dim3(256), 0, stream>>>(Y, gamma, beta, out);
}